// Round 5
// baseline (7701.011 us; speedup 1.0000x reference)
//
#include <hip/hip_runtime.h>

// LSTM: T=1024, B=64, IN=H=512.
// Persistent cooperative kernel: 2 batch-groups x 128 WGs. Each WG owns 4
// hidden units (16 gate rows) for 32 batches; c lives in LDS; weights live in
// registers as MFMA B-fragments.
//
// Per-step h exchange (round 5 = round 4 + DOUBLE-BUFFERED exchange):
//   producers: h written TWICE -- (a) f32 plain cached store to out[t] (the
//              kernel output; nothing in-kernel reads it), (b) f16 into a
//              fragment-layout exchange buffer in workspace, write-through
//              (sc0 sc1) so it lands at the LLC before the flag release.
//   consumers: read the f16 exchange buffer with sc0 sc1 (bypass L1+L2 --
//              REQUIRED: buffers are reused every other step). Layout is
//              exactly the MFMA A-fragment pattern: each consumer wave
//              issues 16 perfectly-coalesced 1KB loads, no f32->f16 CVT on
//              the critical path. 8MB/step total (was 16MB f32 scattered).
//   DOUBLE BUFFER: producer writes ex[t&1]; consumer at iter t reads
//              ex[(t-1)&1]. Single-buffer (round 4) raced: a fast producer's
//              iter-t overwrite vs a skewed consumer's iter-t read of step
//              t-1 data. With parity buffers, overwriting buffer b for step
//              t2 requires all flags >= t2 >= t1+1, and a consumer posts
//              flag t1+1 only AFTER its read of buffer b completed.
//   signaling: per-WG flag dword stores (no atomics -- round 3's single
//              counter serialized 128 RMWs at one LLC bank). flags[grp][128]
//              is a packed 512B array polled by 32 lanes x dwordx4 = one
//              wave-coalesced 8-line request. Flag value = t+1 (monotone).
// NOTE: every inline-asm async-load output is EARLY-CLOBBER ("=&v") -- the
// allocator may otherwise reuse the dead-after-asm address regs as load
// destinations; async return then corrupts later loads' addresses (round-2
// crash).

#define TT 1024
#define BB 64
#define DD 512
#define NBG 2
#define NWG 128
#define HU 4
#define BS 32
#define EXOFF 4096        // byte offset of f16 exchange buffers inside d_ws
#define EXBUF 65536       // one exchange buffer: NBG*2(kh)*16KB

typedef _Float16 half8 __attribute__((ext_vector_type(8)));
typedef float f32x4 __attribute__((ext_vector_type(4)));
typedef int i32x4 __attribute__((ext_vector_type(4)));

__device__ __forceinline__ float sigm(float v) { return 1.0f / (1.0f + __expf(-v)); }
__device__ __forceinline__ float tanh_fast(float v) { return 2.0f / (1.0f + __expf(-2.0f * v)) - 1.0f; }

__device__ __forceinline__ half8 as_half8(f32x4 v) {
    union { f32x4 f; half8 h; } u; u.f = v; return u.h;
}

#define CVT8(DST, LO, HI) do { \
    DST[0] = (_Float16)LO[0]; DST[1] = (_Float16)LO[1]; \
    DST[2] = (_Float16)LO[2]; DST[3] = (_Float16)LO[3]; \
    DST[4] = (_Float16)HI[0]; DST[5] = (_Float16)HI[1]; \
    DST[6] = (_Float16)HI[2]; DST[7] = (_Float16)HI[3]; } while (0)

// 16 fully-coalesced 1KB f16 fragment loads (LLC-direct), one vmcnt(0).
// rr[0..7] = slab s=0 (batch rows l16), rr[8..15] = slab s=1 (rows l16+16);
// within a slab, index = kc (k-chunk of 32).
__device__ __forceinline__ void load_frag16(const char* exb, f32x4 rr[16]) {
    const char* p0 = exb;
    const char* p1 = exb + 4096;
    const char* p2 = exb + 8192;
    const char* p3 = exb + 12288;
    f32x4 r0, r1, r2, r3, r4, r5, r6, r7, r8, r9, r10, r11, r12, r13, r14, r15;
    asm volatile(
        "global_load_dwordx4 %0, %16, off sc0 sc1\n\t"
        "global_load_dwordx4 %1, %16, off offset:1024 sc0 sc1\n\t"
        "global_load_dwordx4 %2, %16, off offset:2048 sc0 sc1\n\t"
        "global_load_dwordx4 %3, %16, off offset:3072 sc0 sc1\n\t"
        "global_load_dwordx4 %4, %17, off sc0 sc1\n\t"
        "global_load_dwordx4 %5, %17, off offset:1024 sc0 sc1\n\t"
        "global_load_dwordx4 %6, %17, off offset:2048 sc0 sc1\n\t"
        "global_load_dwordx4 %7, %17, off offset:3072 sc0 sc1\n\t"
        "global_load_dwordx4 %8, %18, off sc0 sc1\n\t"
        "global_load_dwordx4 %9, %18, off offset:1024 sc0 sc1\n\t"
        "global_load_dwordx4 %10, %18, off offset:2048 sc0 sc1\n\t"
        "global_load_dwordx4 %11, %18, off offset:3072 sc0 sc1\n\t"
        "global_load_dwordx4 %12, %19, off sc0 sc1\n\t"
        "global_load_dwordx4 %13, %19, off offset:1024 sc0 sc1\n\t"
        "global_load_dwordx4 %14, %19, off offset:2048 sc0 sc1\n\t"
        "global_load_dwordx4 %15, %19, off offset:3072 sc0 sc1\n\t"
        "s_waitcnt vmcnt(0)"
        : "=&v"(r0), "=&v"(r1), "=&v"(r2), "=&v"(r3),
          "=&v"(r4), "=&v"(r5), "=&v"(r6), "=&v"(r7),
          "=&v"(r8), "=&v"(r9), "=&v"(r10), "=&v"(r11),
          "=&v"(r12), "=&v"(r13), "=&v"(r14), "=&v"(r15)
        : "v"(p0), "v"(p1), "v"(p2), "v"(p3)
        : "memory");
    rr[0] = r0;  rr[1] = r1;  rr[2] = r2;  rr[3] = r3;
    rr[4] = r4;  rr[5] = r5;  rr[6] = r6;  rr[7] = r7;
    rr[8] = r8;  rr[9] = r9;  rr[10] = r10; rr[11] = r11;
    rr[12] = r12; rr[13] = r13; rr[14] = r14; rr[15] = r15;
}

__global__ __launch_bounds__(256) void lstm_persist(
    const float* __restrict__ x,
    const float* __restrict__ Wxf, const float* __restrict__ Whf,
    const float* __restrict__ Wxi, const float* __restrict__ Whi,
    const float* __restrict__ Wxo, const float* __restrict__ Who,
    const float* __restrict__ Wxg, const float* __restrict__ Whg,
    const float* __restrict__ bxf, const float* __restrict__ bhf,
    const float* __restrict__ bxi, const float* __restrict__ bhi,
    const float* __restrict__ bxo, const float* __restrict__ bho,
    const float* __restrict__ bxg, const float* __restrict__ bhg,
    float* __restrict__ out, int* __restrict__ flags, char* __restrict__ ex)
{
    const int wg   = blockIdx.x;
    const int grp  = wg >> 7;        // batch group 0..1
    const int w    = wg & 127;       // unit-owner index 0..127
    const int tid  = threadIdx.x;
    const int wave = tid >> 6;       // 0,1: x-GEMM halves; 2,3: h-GEMM halves
    const int lane = tid & 63;
    const int quad = lane >> 4;
    const int l16  = lane & 15;

    __shared__ float zbuf[4][BS][17];      // padded: kills LDS bank conflicts
    __shared__ float c_lds[BS][HU];        // persistent cell state
    __shared__ float bias_lds[16];         // bx+bh for our 16 gate rows
    __shared__ _Float16 hlds[BS][HU];      // f16 h staging for ex packing

    if (tid < 128) c_lds[tid >> 2][tid & 3] = 0.0f;
    if (tid < 16) {
        const int g = tid >> 2, u = tid & 3;
        const float* bx = (g == 0) ? bxf : (g == 1) ? bxi : (g == 2) ? bxo : bxg;
        const float* bh = (g == 0) ? bhf : (g == 1) ? bhi : (g == 2) ? bho : bhg;
        bias_lds[tid] = bx[w * HU + u] + bh[w * HU + u];
    }

    // ---- weight B-fragments into registers (once) ----
    const int gate = l16 >> 2;
    const int u    = l16 & 3;
    const float* Wxsel = (gate == 0) ? Wxf : (gate == 1) ? Wxi : (gate == 2) ? Wxo : Wxg;
    const float* Whsel = (gate == 0) ? Whf : (gate == 1) ? Whi : (gate == 2) ? Who : Whg;
    const float* Wsel  = (wave < 2) ? Wxsel : Whsel;
    const int kq  = (wave & 1) << 8;       // this wave's K-quarter base (0 or 256)
    const int row = w * HU + u;
    half8 wfrag[8];
#pragma unroll
    for (int kc = 0; kc < 8; ++kc) {
        const float* p = Wsel + row * DD + kq + kc * 32 + quad * 8;
        half8 f;
#pragma unroll
        for (int j = 0; j < 8; ++j) f[j] = (_Float16)p[j];
        wfrag[kc] = f;
    }

    // ---- precomputed addresses for the exchange path ----
    // consumer base (without buffer select): (grp,kh) block 16KB + lane*16
    const int kh = wave & 1;                       // h-wave K-half
    const char* exb = ex + (size_t)(((grp << 1) | kh) << 14) + (lane << 4);
    // producer target (thread b = tid < 32 packs 4 f16 = 8B per step):
    const int pc0   = w * HU;                      // first col owned by this WG
    const int pkh   = pc0 >> 8;
    const int pkc   = (pc0 >> 5) & 7;
    const int pquad = (pc0 >> 3) & 3;
    const int pjo   = pc0 & 7;                     // 0 or 4
    const int pb    = tid;                         // batch for packer threads
    const int ps    = pb >> 4, plb = pb & 15;
    char* ex_dst = ex
        + (size_t)(((((grp << 1) | pkh) << 1 | ps) * 8 + pkc) << 10)
        + ((pquad << 4 | plb) << 4) + (pjo << 1);
    // flag poll pointer: 32 lanes x int4 covers flags[grp][0..127]
    const int* fb = flags + (grp << 7) + ((lane & 31) << 2);

    __syncthreads();

    const size_t hseq_sz = (size_t)TT * BB * DD;

    for (int t = 0; t < TT; ++t) {
        f32x4 acc0 = {0.f, 0.f, 0.f, 0.f};
        f32x4 acc1 = {0.f, 0.f, 0.f, 0.f};

        if (wave < 2) {
            // x-projection: normal cached loads (L2-resident slices)
            const float* src = x + (size_t)t * BB * DD;
            const float* pa0 = src + (size_t)(grp * BS + l16) * DD + kq + quad * 8;
            const float* pa1 = pa0 + 16 * DD;
#pragma unroll
            for (int kc = 0; kc < 8; ++kc) {
                f32x4 a0lo = *(const f32x4*)(pa0 + kc * 32);
                f32x4 a0hi = *(const f32x4*)(pa0 + kc * 32 + 4);
                f32x4 a1lo = *(const f32x4*)(pa1 + kc * 32);
                f32x4 a1hi = *(const f32x4*)(pa1 + kc * 32 + 4);
                half8 a0, a1;
                CVT8(a0, a0lo, a0hi);
                CVT8(a1, a1lo, a1hi);
                acc0 = __builtin_amdgcn_mfma_f32_16x16x32_f16(a0, wfrag[kc], acc0, 0, 0, 0);
                acc1 = __builtin_amdgcn_mfma_f32_16x16x32_f16(a1, wfrag[kc], acc1, 0, 0, 0);
            }
        } else if (t > 0) {
            // wait for all 128 producers of step t-1: packed-flag poll,
            // one coalesced 8-line LLC request per wave per attempt
            for (;;) {
                i32x4 fv;
                asm volatile("global_load_dwordx4 %0, %1, off sc0 sc1\n\ts_waitcnt vmcnt(0)"
                             : "=&v"(fv) : "v"(fb) : "memory");
                int ok = (lane >= 32) ||
                         (fv[0] >= t && fv[1] >= t && fv[2] >= t && fv[3] >= t);
                if (__all(ok)) break;
                __builtin_amdgcn_s_sleep(1);
            }
            // h-projection: f16 fragments from buffer parity (t-1)&1
            f32x4 rr[16];
            load_frag16(exb + ((size_t)((t & 1) ^ 1) << 16), rr);
#pragma unroll
            for (int kc = 0; kc < 8; ++kc) {
                acc0 = __builtin_amdgcn_mfma_f32_16x16x32_f16(as_half8(rr[kc]),     wfrag[kc], acc0, 0, 0, 0);
                acc1 = __builtin_amdgcn_mfma_f32_16x16x32_f16(as_half8(rr[8 + kc]), wfrag[kc], acc1, 0, 0, 0);
            }
        }

        // D layout: value reg i of lane -> D[row = quad*4+i][col = l16]
#pragma unroll
        for (int i = 0; i < 4; ++i) {
            zbuf[wave][quad * 4 + i][l16]      = acc0[i];
            zbuf[wave][16 + quad * 4 + i][l16] = acc1[i];
        }
        __syncthreads();                                   // (A)

        // ---- elementwise: 128 threads = 32 batches x 4 units ----
        if (tid < 128) {
            const int b = tid >> 2, uu = tid & 3;
            float zf = bias_lds[uu], zi = bias_lds[4 + uu], zo = bias_lds[8 + uu], zg = bias_lds[12 + uu];
#pragma unroll
            for (int wv = 0; wv < 4; ++wv) {
                zf += zbuf[wv][b][uu];
                zi += zbuf[wv][b][4 + uu];
                zo += zbuf[wv][b][8 + uu];
                zg += zbuf[wv][b][12 + uu];
            }
            float ff = sigm(zf), ig = sigm(zi), og = sigm(zo), gg = tanh_fast(zg);
            float c  = ff * c_lds[b][uu] + ig * gg;
            c_lds[b][uu] = c;
            float h  = og * tanh_fast(c);
            const size_t col = (size_t)(grp * BS + b) * DD + (w * HU + uu);
            out[(size_t)t * BB * DD + col] = h;            // plain cached store
            if (t == TT - 1) out[hseq_sz + col] = h;       // final h output
            hlds[b][uu] = (_Float16)h;                     // stage for ex pack
        }
        __syncthreads();                                   // (B)

        // ---- exchange-buffer write: 32 threads x 8B write-through ----
        if (tid < 32) {
            char* dst = ex_dst + ((size_t)(t & 1) << 16);  // buffer parity t&1
            uint2 v = *(const uint2*)(&hlds[pb][0]);
            asm volatile("global_store_dwordx2 %0, %1, off sc0 sc1"
                         :: "v"(dst), "v"(v) : "memory");
        }
        // drain own write-through stores (packers) before flag release
        asm volatile("s_waitcnt vmcnt(0)" ::: "memory");
        __syncthreads();                                   // (C)
        if (tid == 0) {
            int val = t + 1;
            int* fp = flags + (grp << 7) + w;
            asm volatile("global_store_dword %0, %1, off sc0 sc1"
                         :: "v"(fp), "v"(val) : "memory");
        }
    }

    // ---- final c output ----
    if (tid < 128) {
        const int b = tid >> 2, uu = tid & 3;
        out[hseq_sz + BB * DD + (size_t)(grp * BS + b) * DD + (w * HU + uu)] = c_lds[b][uu];
    }
}

extern "C" void kernel_launch(void* const* d_in, const int* in_sizes, int n_in,
                              void* d_out, int out_size, void* d_ws, size_t ws_size,
                              hipStream_t stream) {
    const float* x   = (const float*)d_in[0];
    const float* Wxf = (const float*)d_in[1];  const float* bxf = (const float*)d_in[2];
    const float* Whf = (const float*)d_in[3];  const float* bhf = (const float*)d_in[4];
    const float* Wxi = (const float*)d_in[5];  const float* bxi = (const float*)d_in[6];
    const float* Whi = (const float*)d_in[7];  const float* bhi = (const float*)d_in[8];
    const float* Wxo = (const float*)d_in[9];  const float* bxo = (const float*)d_in[10];
    const float* Who = (const float*)d_in[11]; const float* bho = (const float*)d_in[12];
    const float* Wxg = (const float*)d_in[13]; const float* bxg = (const float*)d_in[14];
    const float* Whg = (const float*)d_in[15]; const float* bhg = (const float*)d_in[16];
    float* out = (float*)d_out;
    int* flags = (int*)d_ws;
    char* ex   = (char*)d_ws + EXOFF;

    // flags are poisoned 0xAA before every timed launch -> zero them.
    // (ex needs no init: buffer parity p is fully written at step t with
    //  p = t&1 before any read of it at step t+1)
    hipMemsetAsync(d_ws, 0, (size_t)NBG * NWG * sizeof(int), stream);

    void* args[] = { &x,
                     &Wxf, &Whf, &Wxi, &Whi, &Wxo, &Who, &Wxg, &Whg,
                     &bxf, &bhf, &bxi, &bhi, &bxo, &bho, &bxg, &bhg,
                     &out, &flags, &ex };
    hipLaunchCooperativeKernel((const void*)lstm_persist,
                               dim3(NBG * NWG), dim3(256), args, 0, stream);
}

// Round 6
// 5222.628 us; speedup vs baseline: 1.4745x; 1.4745x over previous
//
#include <hip/hip_runtime.h>

// LSTM: T=1024, B=64, IN=H=512.
// Round 6: FAT-WG persistent cooperative kernel. 32 WGs x 512 threads
// (16 WGs per batch-group of 32). Each WG owns 32 hidden units = 128 gate
// rows for 32 batches. 8 waves: waves 0-3 = x-GEMM (gate f,i,o,g),
// waves 4-7 = h-GEMM (gate f,i,o,g). Weights persist in registers as MFMA
// B-fragments (2 n-tiles x 16 k-chunks = 128 VGPRs/wave).
//
// Rationale vs rounds 0-5 (256 thin WGs, 6.6-8.4ms): per-step time was
// dominated by the sync fabric -- 256 flag stores, 512 polling waves on 16
// LLC lines, 512 consumer waves doing scattered LLC/L2 h fills. Fat WGs cut
// every contention term 8x while per-WG MFMA work (64/step/wave) is still
// tiny (~0.2us).
//
// h exchange: producers write h f32 to out[t] (the kernel output) with
// write-through (sc0 sc1) stores, drain, then per-WG flag store (value t+1,
// monotone). Consumers poll their group's 16 flags (ONE 64B line, one
// coalesced request) then stage h(t-1) from out with PLAIN CACHED loads:
// legal because out[t-1] addresses are unique per step (never previously
// touched by any cache in this launch -> no stale line possible), and the
// dispatch-boundary acquire invalidates L1/L2 across graph replays (relied
// on since round 1, empirically solid). Coalesced row-major reads, f32->f16
// cvt, staged to LDS; MFMA A-frags then come from LDS conflict-free
// (row stride 520 f16 = 65 x 16B slots, odd -> 8 lanes/slot = floor).

#define TT 1024
#define BB 64
#define DD 512
#define NWG 32
#define HSEQ ((size_t)TT * BB * DD)

typedef _Float16 half8 __attribute__((ext_vector_type(8)));
typedef float f32x4 __attribute__((ext_vector_type(4)));

__device__ __forceinline__ float sigm(float v) { return 1.0f / (1.0f + __expf(-v)); }
__device__ __forceinline__ float tanh_fast(float v) { return 2.0f / (1.0f + __expf(-2.0f * v)) - 1.0f; }

#define CVT8(DST, LO, HI) do { \
    DST[0] = (_Float16)LO[0]; DST[1] = (_Float16)LO[1]; \
    DST[2] = (_Float16)LO[2]; DST[3] = (_Float16)LO[3]; \
    DST[4] = (_Float16)HI[0]; DST[5] = (_Float16)HI[1]; \
    DST[6] = (_Float16)HI[2]; DST[7] = (_Float16)HI[3]; } while (0)

#define MFMA16(A, B, C) __builtin_amdgcn_mfma_f32_16x16x32_f16(A, B, C, 0, 0, 0)

__global__ __launch_bounds__(512, 2) void lstm_persist(
    const float* __restrict__ x,
    const float* __restrict__ Wxf, const float* __restrict__ Whf,
    const float* __restrict__ Wxi, const float* __restrict__ Whi,
    const float* __restrict__ Wxo, const float* __restrict__ Who,
    const float* __restrict__ Wxg, const float* __restrict__ Whg,
    const float* __restrict__ bxf, const float* __restrict__ bhf,
    const float* __restrict__ bxi, const float* __restrict__ bhi,
    const float* __restrict__ bxo, const float* __restrict__ bho,
    const float* __restrict__ bxg, const float* __restrict__ bhg,
    float* __restrict__ out, int* __restrict__ flags)
{
    const int wg   = blockIdx.x;     // 0..31
    const int grp  = wg >> 4;        // batch group 0..1
    const int w    = wg & 15;        // unit-block owner (32 units)
    const int tid  = threadIdx.x;    // 0..511
    const int wid  = tid >> 6;       // 0..7
    const int lane = tid & 63;
    const int quad = lane >> 4;
    const int l16  = lane & 15;
    const int g    = wid & 3;        // gate: 0=f 1=i 2=o 3=g
    const bool is_h = wid >= 4;
    const int sid  = tid & 255;      // id within side (0..255) for staging

    __shared__ _Float16 xlds[32][520];   // x[t] slab, f16 (odd 16B stride)
    __shared__ _Float16 hlds[32][520];   // h[t-1] slab, f16
    __shared__ float zx[4][32][33];      // x-side z partials [gate][b][u]
    __shared__ float zh[4][32][33];      // h-side z partials
    __shared__ float c_lds[32][33];      // persistent cell state [b][u]
    __shared__ float bias_lds[4][32];    // bx+bh [gate][u]

    // ---- init c and bias ----
    {
        const int e = tid * 2, b = e >> 5, u = e & 31;
        c_lds[b][u] = 0.0f; c_lds[b][u + 1] = 0.0f;
    }
    if (tid < 128) {
        const int gg = tid >> 5, uu = tid & 31;
        const float* bx = (gg == 0) ? bxf : (gg == 1) ? bxi : (gg == 2) ? bxo : bxg;
        const float* bh = (gg == 0) ? bhf : (gg == 1) ? bhi : (gg == 2) ? bho : bhg;
        bias_lds[gg][uu] = bx[w * 32 + uu] + bh[w * 32 + uu];
    }

    // ---- weight B-fragments into registers (once): 2 n-tiles x 16 kc ----
    const float* Ws = !is_h
        ? ((g == 0) ? Wxf : (g == 1) ? Wxi : (g == 2) ? Wxo : Wxg)
        : ((g == 0) ? Whf : (g == 1) ? Whi : (g == 2) ? Who : Whg);
    half8 wfrag[2][16];
#pragma unroll
    for (int n = 0; n < 2; ++n)
#pragma unroll
        for (int kc = 0; kc < 16; ++kc) {
            const float* p = Ws + (size_t)(w * 32 + n * 16 + l16) * DD + kc * 32 + quad * 8;
            f32x4 lo = *(const f32x4*)p;
            f32x4 hi = *(const f32x4*)(p + 4);
            half8 f; CVT8(f, lo, hi);
            wfrag[n][kc] = f;
        }

    const float* xbase = x   + (size_t)grp * 32 * DD;   // + t*BB*DD
    const float* obase = out + (size_t)grp * 32 * DD;   // + t*BB*DD
    const int*   fb    = flags + grp * 16 + (lane & 15);

    __syncthreads();

    for (int t = 0; t < TT; ++t) {
        // ---- stage phase ----
        if (!is_h) {
            // x[t] slab: 32 rows x 512 f32, perfectly coalesced, plain cached
            const float* src = xbase + (size_t)t * BB * DD;
#pragma unroll 4
            for (int i = 0; i < 8; ++i) {
                const int flat = i * 2048 + sid * 8;
                const int r = flat >> 9, c = flat & 511;
                const float* p = src + (size_t)r * DD + c;
                f32x4 lo = *(const f32x4*)p;
                f32x4 hi = *(const f32x4*)(p + 4);
                half8 v; CVT8(v, lo, hi);
                *(half8*)&xlds[r][c] = v;
            }
        } else if (t > 0) {
            // wait for all 16 producers of this group (one 64B flag line)
            for (;;) {
                int f;
                asm volatile("global_load_dword %0, %1, off sc0 sc1\n\ts_waitcnt vmcnt(0)"
                             : "=&v"(f) : "v"(fb) : "memory");
                if (__all(f >= t)) break;
                __builtin_amdgcn_s_sleep(1);
            }
            // h[t-1] slab from out: unique-per-step addresses -> cached loads
            const float* src = obase + (size_t)(t - 1) * BB * DD;
#pragma unroll 4
            for (int i = 0; i < 8; ++i) {
                const int flat = i * 2048 + sid * 8;
                const int r = flat >> 9, c = flat & 511;
                const float* p = src + (size_t)r * DD + c;
                f32x4 lo = *(const f32x4*)p;
                f32x4 hi = *(const f32x4*)(p + 4);
                half8 v; CVT8(v, lo, hi);
                *(half8*)&hlds[r][c] = v;
            }
        }
        __syncthreads();                               // (A) stages visible

        // ---- GEMM phase: each wave = one (side, gate), 32 rows x 32 b ----
        f32x4 acc00 = {0.f, 0.f, 0.f, 0.f}, acc01 = {0.f, 0.f, 0.f, 0.f};
        f32x4 acc10 = {0.f, 0.f, 0.f, 0.f}, acc11 = {0.f, 0.f, 0.f, 0.f};
        if (!is_h || t > 0) {
            const _Float16 (*alds)[520] = is_h ? hlds : xlds;
#pragma unroll
            for (int kc = 0; kc < 16; ++kc) {
                half8 a0 = *(const half8*)&alds[l16][kc * 32 + quad * 8];
                half8 a1 = *(const half8*)&alds[16 + l16][kc * 32 + quad * 8];
                acc00 = MFMA16(a0, wfrag[0][kc], acc00);
                acc01 = MFMA16(a0, wfrag[1][kc], acc01);
                acc10 = MFMA16(a1, wfrag[0][kc], acc10);
                acc11 = MFMA16(a1, wfrag[1][kc], acc11);
            }
        }
        // D layout: reg i of lane -> D[row(batch) = quad*4+i][col(u) = l16]
        {
            float (*zb)[33] = is_h ? zh[g] : zx[g];
#pragma unroll
            for (int i = 0; i < 4; ++i) {
                zb[quad * 4 + i][l16]           = acc00[i];
                zb[quad * 4 + i][16 + l16]      = acc01[i];
                zb[16 + quad * 4 + i][l16]      = acc10[i];
                zb[16 + quad * 4 + i][16 + l16] = acc11[i];
            }
        }
        __syncthreads();                               // (B) z complete

        // ---- elementwise: 512 threads x 2 (b,u) elems ----
        {
            const int e = tid * 2, b = e >> 5, u = e & 31;
            float h2[2];
#pragma unroll
            for (int k = 0; k < 2; ++k) {
                const int uu = u + k;
                float zf = bias_lds[0][uu] + zx[0][b][uu] + zh[0][b][uu];
                float zi = bias_lds[1][uu] + zx[1][b][uu] + zh[1][b][uu];
                float zo = bias_lds[2][uu] + zx[2][b][uu] + zh[2][b][uu];
                float zg = bias_lds[3][uu] + zx[3][b][uu] + zh[3][b][uu];
                float c  = sigm(zf) * c_lds[b][uu] + sigm(zi) * tanh_fast(zg);
                c_lds[b][uu] = c;
                h2[k] = sigm(zo) * tanh_fast(c);
            }
            float* hp = out + (size_t)t * BB * DD + (size_t)(grp * 32 + b) * DD + w * 32 + u;
            uint2 hv;
            hv.x = __builtin_bit_cast(unsigned, h2[0]);
            hv.y = __builtin_bit_cast(unsigned, h2[1]);
            // write-through: consumers' cache-miss fills must see it at LLC
            asm volatile("global_store_dwordx2 %0, %1, off sc0 sc1"
                         :: "v"(hp), "v"(hv) : "memory");
            if (t == TT - 1) {
                float* fp2 = out + HSEQ + (size_t)(grp * 32 + b) * DD + w * 32 + u;
                fp2[0] = h2[0]; fp2[1] = h2[1];        // final h output
            }
        }
        // drain own write-through stores, then release
        asm volatile("s_waitcnt vmcnt(0)" ::: "memory");
        __syncthreads();                               // (C) all drained
        if (tid == 0) {
            int val = t + 1;
            int* fp = flags + grp * 16 + w;
            asm volatile("global_store_dword %0, %1, off sc0 sc1"
                         :: "v"(fp), "v"(val) : "memory");
        }
    }

    // ---- final c output ----
    {
        const int e = tid * 2, b = e >> 5, u = e & 31;
        float* cp = out + HSEQ + (size_t)BB * DD + (size_t)(grp * 32 + b) * DD + w * 32 + u;
        cp[0] = c_lds[b][u];
        cp[1] = c_lds[b][u + 1];
    }
}

extern "C" void kernel_launch(void* const* d_in, const int* in_sizes, int n_in,
                              void* d_out, int out_size, void* d_ws, size_t ws_size,
                              hipStream_t stream) {
    const float* x   = (const float*)d_in[0];
    const float* Wxf = (const float*)d_in[1];  const float* bxf = (const float*)d_in[2];
    const float* Whf = (const float*)d_in[3];  const float* bhf = (const float*)d_in[4];
    const float* Wxi = (const float*)d_in[5];  const float* bxi = (const float*)d_in[6];
    const float* Whi = (const float*)d_in[7];  const float* bhi = (const float*)d_in[8];
    const float* Wxo = (const float*)d_in[9];  const float* bxo = (const float*)d_in[10];
    const float* Who = (const float*)d_in[11]; const float* bho = (const float*)d_in[12];
    const float* Wxg = (const float*)d_in[13]; const float* bxg = (const float*)d_in[14];
    const float* Whg = (const float*)d_in[15]; const float* bhg = (const float*)d_in[16];
    float* out = (float*)d_out;
    int* flags = (int*)d_ws;

    // flags are poisoned 0xAA before every timed launch -> zero them
    hipMemsetAsync(d_ws, 0, (size_t)NWG * sizeof(int), stream);

    void* args[] = { &x,
                     &Wxf, &Whf, &Wxi, &Whi, &Wxo, &Who, &Wxg, &Whg,
                     &bxf, &bhf, &bxi, &bhi, &bxo, &bho, &bxg, &bhg,
                     &out, &flags };
    hipLaunchCooperativeKernel((const void*)lstm_persist,
                               dim3(NWG), dim3(512), args, 0, stream);
}

// Round 7
// 5027.964 us; speedup vs baseline: 1.5316x; 1.0387x over previous
//
#include <hip/hip_runtime.h>

// LSTM: T=1024, B=64, IN=H=512.
// Round 7 = Round 6 fat-WG skeleton + three targeted fixes:
//  (1) f16 double-buffered exchange slab: producers cvt h->f16 and WT-store
//      4B/thread into ex[parity][grp][32][512]; consumers cooperatively
//      stage 32KB coalesced LLC-direct (sc0 sc1; REQUIRED: addresses are
//      reused every other step, L2 could hold stale lines). Halves exchange
//      bytes vs reading out[] f32 and removes consumer-side f32->f16 cvt.
//      Parity protocol proven in round 5: producer writes parity t&1 at
//      step t; consumer at step t reads parity (t-1)&1 and only posts flag
//      t+1 after its read completed; a producer reaches its parity-p
//      overwrite at t+2 only after its own h-waves saw all flags >= t+1.
//      The f32 h_seq store to out[t] is no longer read in-kernel -> plain
//      writeback store, off the pre-flag drain path.
//  (2) z/c LDS pad 33->34: (row*34+u)%32 = (2row+u)%32 spreads the
//      elementwise/z access 2-way-free; pad 33 caused the measured 4.2e7
//      SQ_LDS_BANK_CONFLICT.
//  (3) s_setprio(1) on h-waves (poll+stage+GEMM): h-side is the serial
//      critical path; x-waves have ~2x slack (T5 role-split regime).
// Skeleton (round 6, verified): 32 WGs x 512 threads, 16 per batch-group.
// Each WG owns 32 hidden units x 32 batches. Waves 0-3 x-GEMM (gate
// f,i,o,g), waves 4-7 h-GEMM. Weights persist as MFMA B-frags in VGPRs.
// NOTE: all inline-asm async-load outputs EARLY-CLOBBER ("=&v") (round-2).

#define TT 1024
#define BB 64
#define DD 512
#define NWG 32
#define HSEQ ((size_t)TT * BB * DD)
#define EXOFF 4096   // byte offset of exchange slabs in d_ws

typedef _Float16 half8 __attribute__((ext_vector_type(8)));
typedef float f32x4 __attribute__((ext_vector_type(4)));
typedef float f32x2 __attribute__((ext_vector_type(2)));

__device__ __forceinline__ float sigm(float v) { return 1.0f / (1.0f + __expf(-v)); }
__device__ __forceinline__ float tanh_fast(float v) { return 2.0f / (1.0f + __expf(-2.0f * v)) - 1.0f; }

#define CVT8(DST, LO, HI) do { \
    DST[0] = (_Float16)LO[0]; DST[1] = (_Float16)LO[1]; \
    DST[2] = (_Float16)LO[2]; DST[3] = (_Float16)LO[3]; \
    DST[4] = (_Float16)HI[0]; DST[5] = (_Float16)HI[1]; \
    DST[6] = (_Float16)HI[2]; DST[7] = (_Float16)HI[3]; } while (0)

#define MFMA16(A, B, C) __builtin_amdgcn_mfma_f32_16x16x32_f16(A, B, C, 0, 0, 0)

// 8 batched LLC-direct 16B loads (one consumer thread's 128B share of the
// 32KB f16 h-slab), single vmcnt(0).
__device__ __forceinline__ void load_ex8(const char* base, f32x4 r[8]) {
    const char* p0 = base;
    const char* p1 = base + 4096;
    const char* p2 = base + 8192;
    const char* p3 = base + 12288;
    const char* p4 = base + 16384;
    const char* p5 = base + 20480;
    const char* p6 = base + 24576;
    const char* p7 = base + 28672;
    f32x4 a0, a1, a2, a3, a4, a5, a6, a7;
    asm volatile(
        "global_load_dwordx4 %0, %8, off sc0 sc1\n\t"
        "global_load_dwordx4 %1, %9, off sc0 sc1\n\t"
        "global_load_dwordx4 %2, %10, off sc0 sc1\n\t"
        "global_load_dwordx4 %3, %11, off sc0 sc1\n\t"
        "global_load_dwordx4 %4, %12, off sc0 sc1\n\t"
        "global_load_dwordx4 %5, %13, off sc0 sc1\n\t"
        "global_load_dwordx4 %6, %14, off sc0 sc1\n\t"
        "global_load_dwordx4 %7, %15, off sc0 sc1\n\t"
        "s_waitcnt vmcnt(0)"
        : "=&v"(a0), "=&v"(a1), "=&v"(a2), "=&v"(a3),
          "=&v"(a4), "=&v"(a5), "=&v"(a6), "=&v"(a7)
        : "v"(p0), "v"(p1), "v"(p2), "v"(p3), "v"(p4), "v"(p5), "v"(p6), "v"(p7)
        : "memory");
    r[0] = a0; r[1] = a1; r[2] = a2; r[3] = a3;
    r[4] = a4; r[5] = a5; r[6] = a6; r[7] = a7;
}

__global__ __launch_bounds__(512, 2) void lstm_persist(
    const float* __restrict__ x,
    const float* __restrict__ Wxf, const float* __restrict__ Whf,
    const float* __restrict__ Wxi, const float* __restrict__ Whi,
    const float* __restrict__ Wxo, const float* __restrict__ Who,
    const float* __restrict__ Wxg, const float* __restrict__ Whg,
    const float* __restrict__ bxf, const float* __restrict__ bhf,
    const float* __restrict__ bxi, const float* __restrict__ bhi,
    const float* __restrict__ bxo, const float* __restrict__ bho,
    const float* __restrict__ bxg, const float* __restrict__ bhg,
    float* __restrict__ out, int* __restrict__ flags, char* __restrict__ ex)
{
    const int wg   = blockIdx.x;     // 0..31
    const int grp  = wg >> 4;        // batch group 0..1
    const int w    = wg & 15;        // unit-block owner (32 units)
    const int tid  = threadIdx.x;    // 0..511
    const int wid  = tid >> 6;       // 0..7
    const int lane = tid & 63;
    const int quad = lane >> 4;
    const int l16  = lane & 15;
    const int g    = wid & 3;        // gate: 0=f 1=i 2=o 3=g
    const bool is_h = wid >= 4;
    const int sid  = tid & 255;      // id within side (0..255) for staging

    __shared__ _Float16 xlds[32][520];   // x[t] slab, f16
    __shared__ _Float16 hlds[32][520];   // h[t-1] slab, f16
    __shared__ float zx[4][32][34];      // x-side z partials (pad 34: no conflicts)
    __shared__ float zh[4][32][34];      // h-side z partials
    __shared__ float c_lds[32][34];      // persistent cell state
    __shared__ float bias_lds[4][32];    // bx+bh

    // ---- init c and bias ----
    {
        const int e = tid * 2, b = e >> 5, u = e & 31;
        c_lds[b][u] = 0.0f; c_lds[b][u + 1] = 0.0f;
    }
    if (tid < 128) {
        const int gg = tid >> 5, uu = tid & 31;
        const float* bx = (gg == 0) ? bxf : (gg == 1) ? bxi : (gg == 2) ? bxo : bxg;
        const float* bh = (gg == 0) ? bhf : (gg == 1) ? bhi : (gg == 2) ? bho : bhg;
        bias_lds[gg][uu] = bx[w * 32 + uu] + bh[w * 32 + uu];
    }

    // ---- weight B-fragments into registers (once): 2 n-tiles x 16 kc ----
    const float* Ws = !is_h
        ? ((g == 0) ? Wxf : (g == 1) ? Wxi : (g == 2) ? Wxo : Wxg)
        : ((g == 0) ? Whf : (g == 1) ? Whi : (g == 2) ? Who : Whg);
    half8 wfrag[2][16];
#pragma unroll
    for (int n = 0; n < 2; ++n)
#pragma unroll
        for (int kc = 0; kc < 16; ++kc) {
            const float* p = Ws + (size_t)(w * 32 + n * 16 + l16) * DD + kc * 32 + quad * 8;
            f32x4 lo = *(const f32x4*)p;
            f32x4 hi = *(const f32x4*)(p + 4);
            half8 f; CVT8(f, lo, hi);
            wfrag[n][kc] = f;
        }

    const float* xbase = x + (size_t)grp * 32 * DD;     // + t*BB*DD
    const int*   fb    = flags + grp * 16 + (lane & 15);
    // ex slab base for this group (parity added per step): 32KB per slab
    char* exg = ex + ((size_t)grp << 15);

    __syncthreads();

    for (int t = 0; t < TT; ++t) {
        if (is_h) __builtin_amdgcn_s_setprio(1);

        // ---- stage phase ----
        if (!is_h) {
            // x[t] slab: 32 rows x 512 f32, coalesced cached loads, cvt f16
            const float* src = xbase + (size_t)t * BB * DD;
#pragma unroll 4
            for (int i = 0; i < 8; ++i) {
                const int flat = i * 2048 + sid * 8;
                const int r = flat >> 9, c = flat & 511;
                const float* p = src + (size_t)r * DD + c;
                f32x4 lo = *(const f32x4*)p;
                f32x4 hi = *(const f32x4*)(p + 4);
                half8 v; CVT8(v, lo, hi);
                *(half8*)&xlds[r][c] = v;
            }
        } else if (t > 0) {
            // wait for all 16 producers of this group (one 64B flag line)
            for (;;) {
                int f;
                asm volatile("global_load_dword %0, %1, off sc0 sc1\n\ts_waitcnt vmcnt(0)"
                             : "=&v"(f) : "v"(fb) : "memory");
                if (__all(f >= t)) break;
                __builtin_amdgcn_s_sleep(1);
            }
            // h[t-1] f16 slab from exchange: 32KB coalesced LLC-direct
            const char* src = exg + (((t & 1) ^ 1) << 16) + sid * 16;
            f32x4 rr[8];
            load_ex8(src, rr);
#pragma unroll
            for (int i = 0; i < 8; ++i) {
                const int flat = i * 2048 + sid * 8;   // f16 elems
                const int r = flat >> 9, c = flat & 511;
                union { f32x4 f; half8 h; } u; u.f = rr[i];
                *(half8*)&hlds[r][c] = u.h;
            }
        }
        __syncthreads();                               // (A) stages visible

        // ---- GEMM phase: each wave = one (side, gate), 128 rows x 32 b ----
        f32x4 acc00 = {0.f, 0.f, 0.f, 0.f}, acc01 = {0.f, 0.f, 0.f, 0.f};
        f32x4 acc10 = {0.f, 0.f, 0.f, 0.f}, acc11 = {0.f, 0.f, 0.f, 0.f};
        if (!is_h || t > 0) {
            const _Float16 (*alds)[520] = is_h ? hlds : xlds;
#pragma unroll
            for (int kc = 0; kc < 16; ++kc) {
                half8 a0 = *(const half8*)&alds[l16][kc * 32 + quad * 8];
                half8 a1 = *(const half8*)&alds[16 + l16][kc * 32 + quad * 8];
                acc00 = MFMA16(a0, wfrag[0][kc], acc00);
                acc01 = MFMA16(a0, wfrag[1][kc], acc01);
                acc10 = MFMA16(a1, wfrag[0][kc], acc10);
                acc11 = MFMA16(a1, wfrag[1][kc], acc11);
            }
        }
        // D layout: reg i of lane -> D[row(batch) = quad*4+i][col(u) = l16]
        {
            float (*zb)[34] = is_h ? zh[g] : zx[g];
#pragma unroll
            for (int i = 0; i < 4; ++i) {
                zb[quad * 4 + i][l16]           = acc00[i];
                zb[quad * 4 + i][16 + l16]      = acc01[i];
                zb[16 + quad * 4 + i][l16]      = acc10[i];
                zb[16 + quad * 4 + i][16 + l16] = acc11[i];
            }
        }
        if (is_h) __builtin_amdgcn_s_setprio(0);
        __syncthreads();                               // (B) z complete

        // ---- elementwise: 512 threads x 2 (b,u) elems ----
        {
            const int e = tid * 2, b = e >> 5, u = e & 31;
            float h2[2];
#pragma unroll
            for (int k = 0; k < 2; ++k) {
                const int uu = u + k;
                float zf = bias_lds[0][uu] + zx[0][b][uu] + zh[0][b][uu];
                float zi = bias_lds[1][uu] + zx[1][b][uu] + zh[1][b][uu];
                float zo = bias_lds[2][uu] + zx[2][b][uu] + zh[2][b][uu];
                float zg = bias_lds[3][uu] + zx[3][b][uu] + zh[3][b][uu];
                float c  = sigm(zf) * c_lds[b][uu] + sigm(zi) * tanh_fast(zg);
                c_lds[b][uu] = c;
                h2[k] = sigm(zo) * tanh_fast(c);
            }
            // (a) f32 h_seq output: plain writeback store (not read in-kernel)
            float* hp = out + (size_t)t * BB * DD + (size_t)(grp * 32 + b) * DD + w * 32 + u;
            *(f32x2*)hp = (f32x2){h2[0], h2[1]};
            if (t == TT - 1) {
                float* fp2 = out + HSEQ + (size_t)(grp * 32 + b) * DD + w * 32 + u;
                fp2[0] = h2[0]; fp2[1] = h2[1];        // final h output
            }
            // (b) f16 exchange: 4B write-through, lands at LLC before flag
            union { _Float16 h[2]; unsigned u32; } pk;
            pk.h[0] = (_Float16)h2[0]; pk.h[1] = (_Float16)h2[1];
            char* dst = exg + ((t & 1) << 16)
                      + ((size_t)b * 512 + (w * 32 + u)) * 2;
            asm volatile("global_store_dword %0, %1, off sc0 sc1"
                         :: "v"(dst), "v"(pk.u32) : "memory");
        }
        // drain own stores (WT ex-write is the only LLC round trip), release
        asm volatile("s_waitcnt vmcnt(0)" ::: "memory");
        __syncthreads();                               // (C) all drained
        if (tid == 0) {
            int val = t + 1;
            int* fp = flags + grp * 16 + w;
            asm volatile("global_store_dword %0, %1, off sc0 sc1"
                         :: "v"(fp), "v"(val) : "memory");
        }
    }

    // ---- final c output ----
    {
        const int e = tid * 2, b = e >> 5, u = e & 31;
        float* cp = out + HSEQ + (size_t)BB * DD + (size_t)(grp * 32 + b) * DD + w * 32 + u;
        cp[0] = c_lds[b][u];
        cp[1] = c_lds[b][u + 1];
    }
}

extern "C" void kernel_launch(void* const* d_in, const int* in_sizes, int n_in,
                              void* d_out, int out_size, void* d_ws, size_t ws_size,
                              hipStream_t stream) {
    const float* x   = (const float*)d_in[0];
    const float* Wxf = (const float*)d_in[1];  const float* bxf = (const float*)d_in[2];
    const float* Whf = (const float*)d_in[3];  const float* bhf = (const float*)d_in[4];
    const float* Wxi = (const float*)d_in[5];  const float* bxi = (const float*)d_in[6];
    const float* Whi = (const float*)d_in[7];  const float* bhi = (const float*)d_in[8];
    const float* Wxo = (const float*)d_in[9];  const float* bxo = (const float*)d_in[10];
    const float* Who = (const float*)d_in[11]; const float* bho = (const float*)d_in[12];
    const float* Wxg = (const float*)d_in[13]; const float* bxg = (const float*)d_in[14];
    const float* Whg = (const float*)d_in[15]; const float* bhg = (const float*)d_in[16];
    float* out = (float*)d_out;
    int* flags = (int*)d_ws;
    // ex: [parity 0/1][grp 0/1][32 b][512 u] f16; parity stride 64KB,
    // group stride 32KB. Total 128KB at d_ws+4KB.
    char* ex = (char*)d_ws + EXOFF;

    // flags are poisoned 0xAA before every timed launch -> zero them.
    // (ex needs no init: parity p is fully written at step t=p before any
    //  read of it at step t+1)
    hipMemsetAsync(d_ws, 0, (size_t)NWG * sizeof(int), stream);

    void* args[] = { &x,
                     &Wxf, &Whf, &Wxi, &Whi, &Wxo, &Who, &Wxg, &Whg,
                     &bxf, &bhf, &bxi, &bhi, &bxo, &bho, &bxg, &bhg,
                     &out, &flags, &ex };
    hipLaunchCooperativeKernel((const void*)lstm_persist,
                               dim3(NWG), dim3(512), args, 0, stream);
}